// Round 1
// baseline (934.842 us; speedup 1.0000x reference)
//
#include <hip/hip_runtime.h>

// YOLOv1 loss, fp32, pred/labels (N,30,7,7), scalar out = loss/N.
// Layout: element (n,c,s) at n*1470 + c*49 + s, s = i*7+j in [0,49).
//
// v2: LDS-staged. Stage SPB=4 whole samples (pred + labels) per block-group
// with float4 coalesced loads batched 12-deep in registers (max MLP), then
// compute one cell per thread from LDS. Baseline (direct 4B strided loads)
// ran at ~1.0 TB/s effective = latency-bound, not BW-bound.

constexpr int CH     = 49;            // 7*7 cells per channel plane
constexpr int SAMPLE = 30 * CH;       // 1470 floats per sample
constexpr int SPB    = 4;             // samples per group (even -> float4 alignment)
constexpr int GFLOATS = SPB * SAMPLE; // 5880 floats per tensor per group
constexpr int GVEC4   = GFLOATS / 4;  // 1470 float4s per tensor per group
constexpr int STAGE_U = (GVEC4 + 255) / 256;  // 6 unrolled stage steps
constexpr float OBJ_W   = 5.0f;
constexpr float NOOBJ_W = 0.1f;
constexpr float EPS_IOU = 1e-10f;

__device__ __forceinline__ float iou_f(float acx, float acy, float aw, float ah,
                                       float bcx, float bcy, float bw, float bh) {
    float ax1 = acx - aw * 0.5f, ay1 = acy - ah * 0.5f;
    float ax2 = acx + aw * 0.5f, ay2 = acy + ah * 0.5f;
    float bx1 = bcx - bw * 0.5f, by1 = bcy - bh * 0.5f;
    float bx2 = bcx + bw * 0.5f, by2 = bcy + bh * 0.5f;
    float iw = fmaxf(fminf(ax2, bx2) - fmaxf(ax1, bx1), 0.0f);
    float ih = fmaxf(fminf(ay2, by2) - fmaxf(ay1, by1), 0.0f);
    float inter = iw * ih;
    float area_a = (ax2 - ax1) * (ay2 - ay1);
    float area_b = (bx2 - bx1) * (by2 - by1);
    return inter / (area_a + area_b - inter + EPS_IOU);
}

__global__ __launch_bounds__(256) void yolo_loss_kernel(
    const float* __restrict__ pred, const float* __restrict__ lab,
    float* __restrict__ out, int n_samples, float inv_n) {

    __shared__ float sp[GFLOATS];   // staged pred  (4 samples, all 30 ch)
    __shared__ float sl[GFLOATS];   // staged labels (ch 5..8 holes never read)
    __shared__ float wsum[4];       // 256 threads = 4 waves

    const int tid = threadIdx.x;
    float acc = 0.0f;

    const int ngroups = (n_samples + SPB - 1) / SPB;
    for (int g = blockIdx.x; g < ngroups; g += gridDim.x) {
        const int n0 = g * SPB;
        const int nv = min(SPB, n_samples - n0);

        if (nv == SPB) {
            // Fast path: whole group. Base offset g*5880 floats = g*23520 B,
            // 16B-aligned, so float4 views are legal.
            const float4* gp4 = reinterpret_cast<const float4*>(pred + (size_t)n0 * SAMPLE);
            const float4* gl4 = reinterpret_cast<const float4*>(lab  + (size_t)n0 * SAMPLE);
            float4 rp[STAGE_U], rl[STAGE_U];
            bool   pv[STAGE_U], lv[STAGE_U];

            // Issue all pred loads first (up to 12 dwordx4 in flight per lane).
            #pragma unroll
            for (int u = 0; u < STAGE_U; ++u) {
                const int t = tid + u * 256;
                pv[u] = (t < GVEC4);
                if (pv[u]) rp[u] = gp4[t];
            }
            // Label loads: skip vec4s fully inside channels 5..8
            // (per-sample float window [245, 441)).
            #pragma unroll
            for (int u = 0; u < STAGE_U; ++u) {
                const int t = tid + u * 256;
                bool need = false;
                if (t < GVEC4) {
                    const int f   = t << 2;
                    const int k   = f / SAMPLE;        // magic-mul
                    const int off = f - k * SAMPLE;
                    need = (off < 245) || (off > 437);
                    if (need) rl[u] = gl4[t];
                }
                lv[u] = need;
            }
            // Drain into LDS.
            #pragma unroll
            for (int u = 0; u < STAGE_U; ++u) {
                const int t = tid + u * 256;
                if (pv[u]) reinterpret_cast<float4*>(sp)[t] = rp[u];
                if (lv[u]) reinterpret_cast<float4*>(sl)[t] = rl[u];
            }
        } else {
            // Tail group (not hit at N=65536): scalar staging.
            const int nf = nv * SAMPLE;
            const size_t base = (size_t)n0 * SAMPLE;
            for (int t = tid; t < nf; t += 256) {
                sp[t] = pred[base + t];
                sl[t] = lab[base + t];
            }
        }
        __syncthreads();

        const int cells = nv * CH;
        if (tid < cells) {
            const int sidx = tid / CH;
            const int s    = tid - sidx * CH;
            const float* p = sp + sidx * SAMPLE + s;
            const float* l = sl + sidx * SAMPLE + s;

            const float p0 = p[0 * CH], p1 = p[1 * CH], p2 = p[2 * CH], p3 = p[3 * CH];
            const float p4 = p[4 * CH];
            const float p5 = p[5 * CH], p6 = p[6 * CH], p7 = p[7 * CH], p8 = p[8 * CH];
            const float p9 = p[9 * CH];
            const float l0 = l[0 * CH], l1 = l[1 * CH], l2 = l[2 * CH], l3 = l[3 * CH];
            const float l4 = l[4 * CH];
            const float l9 = l[9 * CH];

            const float iou1 = iou_f(p0, p1, p2, p3, l0, l1, l2, l3);
            const float iou2 = iou_f(p5, p6, p7, p8, l0, l1, l2, l3);
            const bool  sel1 = iou1 >= iou2;
            const float objf = (l4 == 1.0f) ? 1.0f : 0.0f;

            const float dconf = sel1 ? (p4 - l4) : (p9 - l9);
            const float conf  = dconf * dconf;

            const float dni       = sel1 ? (p9 - iou1) : (p4 - iou2);
            const float noobj_in  = dni * dni;
            const float noobj_out = p4 * p4 + p9 * p9;

            const float bx = sel1 ? p0 : p5, by = sel1 ? p1 : p6;
            const float bw = sel1 ? p2 : p7, bh = sel1 ? p3 : p8;
            const float dx = bx - l0, dy = by - l1;
            const float dw = sqrtf(bw) - sqrtf(l2);
            const float dh = sqrtf(bh) - sqrtf(l3);
            const float bbox = dx * dx + dy * dy + dw * dw + dh * dh;

            float cls = 0.0f;
            #pragma unroll
            for (int c = 10; c < 30; ++c) {
                const float d = p[c * CH] - l[c * CH];
                cls += d * d;
            }

            acc += objf * (conf + OBJ_W * bbox + cls + NOOBJ_W * noobj_in)
                 + (1.0f - objf) * (NOOBJ_W * noobj_out);
        }
        __syncthreads();   // LDS reuse by next group
    }

    // wave64 reduce
    #pragma unroll
    for (int off = 32; off > 0; off >>= 1)
        acc += __shfl_down(acc, off, 64);

    const int lane = tid & 63;
    const int wid  = tid >> 6;
    if (lane == 0) wsum[wid] = acc;
    __syncthreads();
    if (tid == 0) {
        const float bsum = wsum[0] + wsum[1] + wsum[2] + wsum[3];
        atomicAdd(out, bsum * inv_n);
    }
}

extern "C" void kernel_launch(void* const* d_in, const int* in_sizes, int n_in,
                              void* d_out, int out_size, void* d_ws, size_t ws_size,
                              hipStream_t stream) {
    const float* pred = (const float*)d_in[0];
    const float* lab  = (const float*)d_in[1];
    float* out = (float*)d_out;

    const int N = in_sizes[0] / SAMPLE;      // 65536

    // d_out is poisoned 0xAA before every timed launch — zero it on-stream.
    hipMemsetAsync(out, 0, sizeof(float), stream);

    const int block = 256;
    const int grid  = 2048;                  // 16384 groups -> 8 groups/block
    yolo_loss_kernel<<<grid, block, 0, stream>>>(pred, lab, out, N, 1.0f / (float)N);
}

// Round 2
// 698.735 us; speedup vs baseline: 1.3379x; 1.3379x over previous
//
#include <hip/hip_runtime.h>

// YOLOv1 loss, fp32, pred/labels (N,30,7,7), scalar out = loss/N.
// Layout: element (n,c,s) at n*1470 + c*49 + s, s in [0,49).
//
// v3: wave-per-sample, NO block barriers in the main loop.
//  - Only the 16 "control" channels (pred 0-9, labels 0-4 and 9) are staged
//    through wave-private LDS (cross-lane gather needed for IOU/conf/bbox).
//  - Channels 10-29 of pred+labels (2/3 of all traffic) stream directly
//    global->register as float2 and are combined elementwise using a
//    49-bit per-sample obj mask broadcast via __ballot (wave-uniform).
//  - Software pipeline: stage-loads(k+1) + elem-loads(k) issued before the
//    LDS write / compute of sample k -> ~23 independent 512B wave-loads in
//    flight, no vmcnt(0) drains, no __syncthreads convoy.

constexpr int CH     = 49;
constexpr int SAMPLE = 30 * CH;       // 1470 floats
constexpr int NW     = 4;             // waves per 256-thread block
constexpr float OBJ_W   = 5.0f;
constexpr float NOOBJ_W = 0.1f;
constexpr float EPS_IOU = 1e-10f;

// (128*r) % 49 for the elementwise mod-49 cell index
__constant__ int KMOD_dummy[1]; // (placeholder, constants inlined below)

__device__ __forceinline__ float iou_f(float acx, float acy, float aw, float ah,
                                       float bcx, float bcy, float bw, float bh) {
    float ax1 = acx - aw * 0.5f, ay1 = acy - ah * 0.5f;
    float ax2 = acx + aw * 0.5f, ay2 = acy + ah * 0.5f;
    float bx1 = bcx - bw * 0.5f, by1 = bcy - bh * 0.5f;
    float bx2 = bcx + bw * 0.5f, by2 = bcy + bh * 0.5f;
    float iw = fmaxf(fminf(ax2, bx2) - fmaxf(ax1, bx1), 0.0f);
    float ih = fmaxf(fminf(ay2, by2) - fmaxf(ay1, by1), 0.0f);
    float inter = iw * ih;
    float area_a = (ax2 - ax1) * (ay2 - ay1);
    float area_b = (bx2 - bx1) * (by2 - by1);
    return inter / (area_a + area_b - inter + EPS_IOU);
}

__global__ __launch_bounds__(256) void yolo_loss_kernel(
    const float* __restrict__ pred, const float* __restrict__ lab,
    float* __restrict__ out, int n_samples, float inv_n) {

    // wave-private staging: pred floats [0,490), labels floats [0,246)+[440,490)
    __shared__ float sp[NW][490];
    __shared__ float sl[NW][490];
    __shared__ float wsum[NW];

    const int tid  = threadIdx.x;
    const int lane = tid & 63;
    const int w    = tid >> 6;
    float* SP = sp[w];
    float* SL = sl[w];

    const int gw      = blockIdx.x * NW + w;   // global wave id
    const int gstride = gridDim.x * NW;

    float acc = 0.0f;

    // stage loads for control channels of one sample into named regs
    auto issue_stage = [&](int k, float2 (&RP)[4], float2 (&RL)[3]) {
        const float2* bp = reinterpret_cast<const float2*>(pred + (size_t)k * SAMPLE);
        const float2* bl = reinterpret_cast<const float2*>(lab  + (size_t)k * SAMPLE);
        #pragma unroll
        for (int r = 0; r < 4; ++r) {            // pred floats [0,490) = 245 f2
            const int i = lane + 64 * r;
            if (i < 245) RP[r] = bp[i];
        }
        #pragma unroll
        for (int r = 0; r < 2; ++r) {            // labels floats [0,246) = 123 f2
            const int i = lane + 64 * r;
            if (i < 123) RL[r] = bl[i];
        }
        if (lane < 25) RL[2] = bl[220 + lane];   // labels floats [440,490)
    };

    // full processing of sample k whose control regs are in (RP,RL)
    auto process = [&](int k, float2 (&RP)[4], float2 (&RL)[3]) {
        const float2* bp = reinterpret_cast<const float2*>(pred + (size_t)k * SAMPLE);
        const float2* bl = reinterpret_cast<const float2*>(lab  + (size_t)k * SAMPLE);

        // 1) issue elementwise loads for this sample: float2 idx [245,735)
        float2 ep[8], el[8];
        #pragma unroll
        for (int r = 0; r < 8; ++r) {
            const int j = 245 + lane + 64 * r;
            if (j < 735) { ep[r] = bp[j]; el[r] = bl[j]; }
        }

        // 2) drain control regs into wave-private LDS (waits only this wave's
        //    stage loads, issued one iteration ago -> latency already covered)
        #pragma unroll
        for (int r = 0; r < 4; ++r) {
            const int i = lane + 64 * r;
            if (i < 245) reinterpret_cast<float2*>(SP)[i] = RP[r];
        }
        #pragma unroll
        for (int r = 0; r < 2; ++r) {
            const int i = lane + 64 * r;
            if (i < 123) reinterpret_cast<float2*>(SL)[i] = RL[r];
        }
        if (lane < 25) reinterpret_cast<float2*>(SL)[220 + lane] = RL[2];

        // wave-synchronous LDS visibility (lanes run in lockstep; just need
        // the memory ordering). No __syncthreads.
        asm volatile("s_waitcnt lgkmcnt(0)" ::: "memory");
        __builtin_amdgcn_sched_barrier(0);

        // 3) control phase: lanes 0..48 each own one cell
        bool obj = false;
        if (lane < CH) {
            const int s = lane;
            const float p0 = SP[0*CH+s], p1 = SP[1*CH+s], p2 = SP[2*CH+s], p3 = SP[3*CH+s];
            const float p4 = SP[4*CH+s];
            const float p5 = SP[5*CH+s], p6 = SP[6*CH+s], p7 = SP[7*CH+s], p8 = SP[8*CH+s];
            const float p9 = SP[9*CH+s];
            const float l0 = SL[0*CH+s], l1 = SL[1*CH+s], l2 = SL[2*CH+s], l3 = SL[3*CH+s];
            const float l4 = SL[4*CH+s];
            const float l9 = SL[9*CH+s];

            const float iou1 = iou_f(p0, p1, p2, p3, l0, l1, l2, l3);
            const float iou2 = iou_f(p5, p6, p7, p8, l0, l1, l2, l3);
            const bool  sel1 = iou1 >= iou2;
            obj = (l4 == 1.0f);
            const float objf = obj ? 1.0f : 0.0f;

            const float dconf = sel1 ? (p4 - l4) : (p9 - l9);
            const float dni   = sel1 ? (p9 - iou1) : (p4 - iou2);
            const float noobj_out = p4 * p4 + p9 * p9;

            const float bx = sel1 ? p0 : p5, by = sel1 ? p1 : p6;
            const float bw = sel1 ? p2 : p7, bh = sel1 ? p3 : p8;
            const float dx = bx - l0, dy = by - l1;
            const float dw = sqrtf(bw) - sqrtf(l2);
            const float dh = sqrtf(bh) - sqrtf(l3);
            const float bbox = dx * dx + dy * dy + dw * dw + dh * dh;

            acc += objf * (dconf * dconf + OBJ_W * bbox + NOOBJ_W * dni * dni)
                 + (1.0f - objf) * (NOOBJ_W * noobj_out);
        }
        // 49-bit obj mask, wave-uniform
        const unsigned long long om = __ballot(lane < CH && obj);

        // 4) elementwise phase: channels 10..29 of pred/labels, objf-weighted
        //    float f within elem region = 2*lane + 128*r; cell s = f % 49
        constexpr int KM[8] = {0, 30, 11, 41, 22, 3, 33, 14}; // (128r)%49
        #pragma unroll
        for (int r = 0; r < 8; ++r) {
            const int j = 245 + lane + 64 * r;
            if (j < 735) {
                int s0 = 2 * lane + KM[r];        // < 196
                if (s0 >= 98) s0 -= 98;
                if (s0 >= 49) s0 -= 49;
                int s1 = s0 + 1;
                if (s1 == 49) s1 = 0;
                const float d0 = ep[r].x - el[r].x;
                const float d1 = ep[r].y - el[r].y;
                const float w0 = ((om >> s0) & 1ull) ? 1.0f : 0.0f;
                const float w1 = ((om >> s1) & 1ull) ? 1.0f : 0.0f;
                acc = fmaf(w0 * d0, d0, acc);
                acc = fmaf(w1 * d1, d1, acc);
            }
        }
    };

    // software pipeline over this wave's samples (A/B named reg sets ->
    // all array indexing is compile-time; no scratch)
    float2 rpA[4], rlA[3], rpB[4], rlB[3];
    int k = gw;
    if (k < n_samples) {
        issue_stage(k, rpA, rlA);
        while (true) {
            int kn = k + gstride;
            if (kn < n_samples) issue_stage(kn, rpB, rlB);
            process(k, rpA, rlA);
            k = kn;
            if (k >= n_samples) break;
            kn = k + gstride;
            if (kn < n_samples) issue_stage(kn, rpA, rlA);
            process(k, rpB, rlB);
            k = kn;
            if (k >= n_samples) break;
        }
    }

    // wave64 reduce + block reduce
    #pragma unroll
    for (int off = 32; off > 0; off >>= 1)
        acc += __shfl_down(acc, off, 64);

    if (lane == 0) wsum[w] = acc;
    __syncthreads();
    if (tid == 0) {
        const float bsum = wsum[0] + wsum[1] + wsum[2] + wsum[3];
        atomicAdd(out, bsum * inv_n);
    }
}

extern "C" void kernel_launch(void* const* d_in, const int* in_sizes, int n_in,
                              void* d_out, int out_size, void* d_ws, size_t ws_size,
                              hipStream_t stream) {
    const float* pred = (const float*)d_in[0];
    const float* lab  = (const float*)d_in[1];
    float* out = (float*)d_out;

    const int N = in_sizes[0] / SAMPLE;      // 65536

    // d_out is poisoned 0xAA before every timed launch — zero it on-stream.
    hipMemsetAsync(out, 0, sizeof(float), stream);

    const int block = 256;
    const int grid  = 2048;                  // 8192 waves -> 8 samples/wave
    yolo_loss_kernel<<<grid, block, 0, stream>>>(pred, lab, out, N, 1.0f / (float)N);
}

// Round 3
// 693.551 us; speedup vs baseline: 1.3479x; 1.0075x over previous
//
#include <hip/hip_runtime.h>

// YOLOv1 loss, fp32, pred/labels (N,30,7,7), scalar out = loss/N.
// Layout: element (n,c,s) at n*1470 + c*49 + s, s in [0,49).
//
// v4: wave-per-sample, no block barriers, FULL-iteration software pipeline.
//  - issue_all(k): 7 control float2 loads + 16 elem float2 loads into a named
//    register set (A/B). Issued one full iteration before consumption, so every
//    s_waitcnt (compiler-counted, precise per-register) is already satisfied.
//  - Control channels (pred 0-9, labels 0-4,9) go regs->LDS (wave-private, no
//    __syncthreads; compiler orders ds_write->ds_read with lgkmcnt).
//  - Elem channels 10..29 (2/3 of traffic) stream global->reg, weighted by a
//    49-float per-wave objf table (replaces 64-bit ballot-mask shifts).
//  - Per-lane cell indices s0/s1[r] are sample-invariant: computed once.

constexpr int CH     = 49;
constexpr int SAMPLE = 30 * CH;       // 1470 floats
constexpr int NW     = 4;             // waves per 256-thread block
constexpr float OBJ_W   = 5.0f;
constexpr float NOOBJ_W = 0.1f;
constexpr float EPS_IOU = 1e-10f;

__device__ __forceinline__ float iou_f(float acx, float acy, float aw, float ah,
                                       float bcx, float bcy, float bw, float bh) {
    float ax1 = acx - aw * 0.5f, ay1 = acy - ah * 0.5f;
    float ax2 = acx + aw * 0.5f, ay2 = acy + ah * 0.5f;
    float bx1 = bcx - bw * 0.5f, by1 = bcy - bh * 0.5f;
    float bx2 = bcx + bw * 0.5f, by2 = bcy + bh * 0.5f;
    float iw = fmaxf(fminf(ax2, bx2) - fmaxf(ax1, bx1), 0.0f);
    float ih = fmaxf(fminf(ay2, by2) - fmaxf(ay1, by1), 0.0f);
    float inter = iw * ih;
    float area_a = (ax2 - ax1) * (ay2 - ay1);
    float area_b = (bx2 - bx1) * (by2 - by1);
    return inter / (area_a + area_b - inter + EPS_IOU);
}

struct Regs {
    float2 rp[4];          // pred ctrl:  float2 [0,245)
    float2 rl[3];          // labels ctrl: float2 [0,123) + [220,245)
    float2 ep[8], el[8];   // elem: float2 [245,735) of pred/labels
};

__global__ __launch_bounds__(256) void yolo_loss_kernel(
    const float* __restrict__ pred, const float* __restrict__ lab,
    float* __restrict__ out, int n_samples, float inv_n) {

    __shared__ float sp[NW][490];
    __shared__ float sl[NW][490];
    __shared__ float sobj[NW][CH];
    __shared__ float wsum[NW];

    const int tid  = threadIdx.x;
    const int lane = tid & 63;
    const int w    = tid >> 6;
    float* SP   = sp[w];
    float* SL   = sl[w];
    float* SOBJ = sobj[w];

    const int gw = blockIdx.x * NW + w;
    const int gs = gridDim.x * NW;

    // per-lane cell indices for the elem region: sample-invariant.
    // elem float index = 490 + 2*lane + 128*r  ->  s0 = (2*lane + (128r)%49) % 49
    int s0[8], s1[8];
    {
        const int km[8] = {0, 30, 11, 41, 22, 3, 33, 14};
        #pragma unroll
        for (int r = 0; r < 8; ++r) {
            int a = 2 * lane + km[r];            // <= 167
            a = (a >= 98) ? a - 98 : a;
            a = (a >= 49) ? a - 49 : a;
            s0[r] = a;
            s1[r] = (a == 48) ? 0 : a + 1;
        }
    }

    float acc = 0.0f;

    auto issue_all = [&](int k, Regs& R) {
        const float2* bp = reinterpret_cast<const float2*>(pred + (size_t)k * SAMPLE);
        const float2* bl = reinterpret_cast<const float2*>(lab  + (size_t)k * SAMPLE);
        #pragma unroll
        for (int r = 0; r < 4; ++r) {
            const int i = lane + 64 * r;
            if (i < 245) R.rp[r] = bp[i];
        }
        #pragma unroll
        for (int r = 0; r < 2; ++r) {
            const int i = lane + 64 * r;
            if (i < 123) R.rl[r] = bl[i];
        }
        if (lane < 25) R.rl[2] = bl[220 + lane];
        #pragma unroll
        for (int r = 0; r < 8; ++r) {
            const int j = 245 + lane + 64 * r;
            if (j < 735) { R.ep[r] = bp[j]; R.el[r] = bl[j]; }
        }
    };

    auto process = [&](Regs& R) {
        // drain ctrl regs into wave-private LDS (regs loaded a full iteration ago)
        #pragma unroll
        for (int r = 0; r < 4; ++r) {
            const int i = lane + 64 * r;
            if (i < 245) reinterpret_cast<float2*>(SP)[i] = R.rp[r];
        }
        #pragma unroll
        for (int r = 0; r < 2; ++r) {
            const int i = lane + 64 * r;
            if (i < 123) reinterpret_cast<float2*>(SL)[i] = R.rl[r];
        }
        if (lane < 25) reinterpret_cast<float2*>(SL)[220 + lane] = R.rl[2];

        // control phase: lanes 0..48 own one cell each
        if (lane < CH) {
            const int s = lane;
            const float p0 = SP[0*CH+s], p1 = SP[1*CH+s], p2 = SP[2*CH+s], p3 = SP[3*CH+s];
            const float p4 = SP[4*CH+s];
            const float p5 = SP[5*CH+s], p6 = SP[6*CH+s], p7 = SP[7*CH+s], p8 = SP[8*CH+s];
            const float p9 = SP[9*CH+s];
            const float l0 = SL[0*CH+s], l1 = SL[1*CH+s], l2 = SL[2*CH+s], l3 = SL[3*CH+s];
            const float l4 = SL[4*CH+s];
            const float l9 = SL[9*CH+s];

            const float iou1 = iou_f(p0, p1, p2, p3, l0, l1, l2, l3);
            const float iou2 = iou_f(p5, p6, p7, p8, l0, l1, l2, l3);
            const bool  sel1 = iou1 >= iou2;
            const float objf = (l4 == 1.0f) ? 1.0f : 0.0f;

            SOBJ[lane] = objf;   // objf table for the elem phase

            const float dconf = sel1 ? (p4 - l4) : (p9 - l9);
            const float dni   = sel1 ? (p9 - iou1) : (p4 - iou2);
            const float noobj_out = p4 * p4 + p9 * p9;

            const float bx = sel1 ? p0 : p5, by = sel1 ? p1 : p6;
            const float bw = sel1 ? p2 : p7, bh = sel1 ? p3 : p8;
            const float dx = bx - l0, dy = by - l1;
            const float dw = sqrtf(bw) - sqrtf(l2);
            const float dh = sqrtf(bh) - sqrtf(l3);
            const float bbox = dx * dx + dy * dy + dw * dw + dh * dh;

            acc += objf * (dconf * dconf + OBJ_W * bbox + NOOBJ_W * dni * dni)
                 + (1.0f - objf) * (NOOBJ_W * noobj_out);
        }

        // elem phase: channels 10..29, objf-weighted via the LDS table
        #pragma unroll
        for (int r = 0; r < 8; ++r) {
            const int j = 245 + lane + 64 * r;
            if (j < 735) {
                const float w0 = SOBJ[s0[r]];
                const float w1 = SOBJ[s1[r]];
                const float d0 = R.ep[r].x - R.el[r].x;
                const float d1 = R.ep[r].y - R.el[r].y;
                acc = fmaf(w0 * d0, d0, acc);
                acc = fmaf(w1 * d1, d1, acc);
            }
        }
    };

    // software pipeline: all loads for sample k+1 issued before process(k).
    Regs A, B;
    int k = gw;
    if (k < n_samples) {
        issue_all(k, A);
        while (true) {
            int kn = k + gs;
            if (kn < n_samples) issue_all(kn, B);
            process(A);
            if (kn >= n_samples) break;
            k = kn;
            kn = k + gs;
            if (kn < n_samples) issue_all(kn, A);
            process(B);
            if (kn >= n_samples) break;
            k = kn;
        }
    }

    // wave64 reduce + block reduce
    #pragma unroll
    for (int off = 32; off > 0; off >>= 1)
        acc += __shfl_down(acc, off, 64);

    if (lane == 0) wsum[w] = acc;
    __syncthreads();
    if (tid == 0) {
        const float bsum = wsum[0] + wsum[1] + wsum[2] + wsum[3];
        atomicAdd(out, bsum * inv_n);
    }
}

extern "C" void kernel_launch(void* const* d_in, const int* in_sizes, int n_in,
                              void* d_out, int out_size, void* d_ws, size_t ws_size,
                              hipStream_t stream) {
    const float* pred = (const float*)d_in[0];
    const float* lab  = (const float*)d_in[1];
    float* out = (float*)d_out;

    const int N = in_sizes[0] / SAMPLE;      // 65536

    // d_out is poisoned 0xAA before every timed launch — zero it on-stream.
    hipMemsetAsync(out, 0, sizeof(float), stream);

    const int block = 256;
    const int grid  = 2048;                  // 8192 waves -> 8 samples/wave
    yolo_loss_kernel<<<grid, block, 0, stream>>>(pred, lab, out, N, 1.0f / (float)N);
}